// Round 19
// baseline (90.643 us; speedup 1.0000x reference)
//
#include <hip/hip_runtime.h>
#include <hip/hip_bf16.h>
#include <stdint.h>

// Problem: B=64, N=32, D=512, P=992 pairs, M = B*P = 63488.
// out[m,d] = relu(U[i(m)] + V[j(m)])·W2[d,:] + b2[d]
// U = pf @ W1[:,:512]^T (+b1), V = pf @ W1[:,512:]^T   (only 2048 distinct rows)
//
// Config ledger:
//   R7:  BN<512 col-split -> L2 thrash. BN=512 mandatory.
//   R8:  2 independent blocks/CU give phase overlap; 1 barrier-locked block
//        serializes (R4-R6, re-confirmed R14).
//   R9:  ping-pong guards must cover the LAST consumer.
//   R11: __launch_bounds__ 2nd arg = waves per SIMD, NOT blocks/CU.
//   R13: B global->VGPR; lgkm-only barrier lets prefetch ride through.
//   R14: BM=128 -> 1 block/CU -> regressed. acc=128 + 2 blocks/CU is fixed.
//   R15: NT stores regressed. R16: setprio removal regressed (keep setprio).
//   R18: bf16 UV end-to-end: 73.4 -> 71.6 us (traffic model holds).
//   R19: two sequential tiles per block; tile-0 stores drain under tile-1
//        compute (store-tail overlap; R6 retry now that blocks are 4-wave).

typedef __attribute__((ext_vector_type(4))) float f32x4;
typedef __attribute__((ext_vector_type(8))) short bf16x8;
typedef __attribute__((ext_vector_type(4))) unsigned int u32x4;

__device__ __forceinline__ uint32_t cvt2_bf16(float a, float b) {
    __hip_bfloat162 h = __float22bfloat162_rn(make_float2(a, b));
    uint32_t u;
    __builtin_memcpy(&u, &h, 4);
    return u;
}

// ---------------------------------------------------------------------------
// Kernel 1 (merged): blocks 0..511 -> uv_gemm 32x128 tiles (2.5 blocks/CU);
// blocks 512..639 -> W2 rearrange into MFMA-fragment order (32768 16B slots):
//   slot s: l = s&63, fn = (s>>6)&31, kt = s>>11
//   col = fn*16 + (l&15), k = kt*32 + (l>>4)*8
// UV stored in BF16: UVb[row][0..511]=U row (b1 folded), [512..1023]=V.
// ---------------------------------------------------------------------------
__global__ __launch_bounds__(256) void prep(const float* __restrict__ pf,
                                            const float* __restrict__ W1,
                                            const float* __restrict__ b1,
                                            const float* __restrict__ W2,
                                            unsigned short* __restrict__ UVb,
                                            unsigned short* __restrict__ W2r) {
    __shared__ unsigned short As[32][64];
    __shared__ unsigned short Bs[128][64];

    const int t = threadIdx.x;
    const int bxg = blockIdx.x;

    if (bxg >= 512) {
        int s = (bxg - 512) * 256 + t;           // 0..32767
        int l = s & 63;
        int fn = (s >> 6) & 31;
        int kt = s >> 11;
        int col = fn * 16 + (l & 15);
        int k = kt * 32 + (l >> 4) * 8;
        const float* src = W2 + (size_t)col * 512 + k;
        f32x4 a = ((const f32x4*)src)[0];
        f32x4 b = ((const f32x4*)src)[1];
        u32x4 P;
        P[0] = cvt2_bf16(a[0], a[1]); P[1] = cvt2_bf16(a[2], a[3]);
        P[2] = cvt2_bf16(b[0], b[1]); P[3] = cvt2_bf16(b[2], b[3]);
        *(u32x4*)(W2r + (size_t)s * 8) = P;
        return;
    }

    // ---- uv_gemm: 32x128 tile, BK=64, 4 waves (2M x 2N), XOR-swizzled LDS
    const int m0 = (bxg >> 3) * 32;              // 64 m-tiles
    const int c0 = (bxg & 7) * 128;              // 8 col tiles

    const int row8 = t >> 3;                     // 0..31
    const int g = t & 7;                         // 16B granule (8 floats)

    const int wave = t >> 6, lane = t & 63;
    const int wr = wave >> 1, wc = wave & 1;
    const int lr = lane & 15, lkq = lane >> 4;
    const int s7 = lr & 7;

    f32x4 acc[4] = {};

    const float* a_src = pf + (size_t)(m0 + row8) * 512 + g * 8;
    const float* b_src[4];
    int wbB[4];
#pragma unroll
    for (int p = 0; p < 4; ++p) {
        int rb = p * 32 + row8;
        int c = c0 + rb;
        int d = c & 511;
        int koff = (c >> 9) * 512;
        b_src[p] = W1 + (size_t)d * 1024 + koff + g * 8;
        wbB[p] = rb * 128 + ((g ^ (rb & 7)) << 4);
    }
    const int wbA = row8 * 128 + ((g ^ (row8 & 7)) << 4);

    for (int kt = 0; kt < 512; kt += 64) {
        {
            const float* gp = a_src + kt;
            f32x4 x0 = ((const f32x4*)gp)[0];
            f32x4 x1 = ((const f32x4*)gp)[1];
            u32x4 P;
            P[0] = cvt2_bf16(x0[0], x0[1]); P[1] = cvt2_bf16(x0[2], x0[3]);
            P[2] = cvt2_bf16(x1[0], x1[1]); P[3] = cvt2_bf16(x1[2], x1[3]);
            *(u32x4*)((char*)&As[0][0] + wbA) = P;
        }
#pragma unroll
        for (int p = 0; p < 4; ++p) {
            const float* gp = b_src[p] + kt;
            f32x4 x0 = ((const f32x4*)gp)[0];
            f32x4 x1 = ((const f32x4*)gp)[1];
            u32x4 P;
            P[0] = cvt2_bf16(x0[0], x0[1]); P[1] = cvt2_bf16(x0[2], x0[3]);
            P[2] = cvt2_bf16(x1[0], x1[1]); P[3] = cvt2_bf16(x1[2], x1[3]);
            *(u32x4*)((char*)&Bs[0][0] + wbB[p]) = P;
        }
        __syncthreads();
#pragma unroll
        for (int kk = 0; kk < 2; ++kk) {
            const int co = (((kk << 2) + lkq) ^ s7) << 3;    // ushort offset
            bf16x8 af = *(const bf16x8*)(&As[0][0] + (wr * 16 + lr) * 64 + co);
#pragma unroll
            for (int n = 0; n < 4; ++n) {
                bf16x8 bfr = *(const bf16x8*)(&Bs[0][0] + (wc * 64 + n * 16 + lr) * 64 + co);
                acc[n] = __builtin_amdgcn_mfma_f32_16x16x32_bf16(af, bfr, acc[n], 0, 0, 0);
            }
        }
        __syncthreads();
    }

    const int cr = lane >> 4;
    const int cc = lane & 15;
#pragma unroll
    for (int n = 0; n < 4; ++n) {
        int c = c0 + wc * 64 + n * 16 + cc;
        float bias = (c < 512) ? b1[c] : 0.0f;
        int rowb = m0 + wr * 16 + cr * 4;
#pragma unroll
        for (int r_ = 0; r_ < 4; ++r_)
            UVb[(size_t)(rowb + r_) * 1024 + c] =
                (unsigned short)(cvt2_bf16(acc[n][r_] + bias, 0.0f) & 0xFFFFu);
    }
}

// ---------------------------------------------------------------------------
// Kernel 2: out = relu(U[i]+V[j]) @ W2^T + b2.  (R18 structure, two tiles
// per block: steps 0-15 -> rows [m0A,m0A+64), 16-31 -> [m0B,m0B+64).
// Tile-0 epilogue issued after step 15; its HBM drain overlaps tile-1.
// BM=64, BN=512, BK=32. 256 thr = 4 waves, wave tile 64x128, 2 blocks/CU.
// B: global->VGPR dbuf (chunk = S&15). UV: bf16 depth-2 ping-pong, pointer
// selected by S>=16. A: 8 KB frag-major dbuf LDS; lgkm-only barrier.
// Grid 496 = 8 XCD x 62 pairs (UV 512KB + W2r 512KB resident per XCD L2).
// ---------------------------------------------------------------------------
__global__ __launch_bounds__(256, 2) void fused_gemm(const unsigned short* __restrict__ UVb,
                                                     const unsigned short* __restrict__ W2r,
                                                     const float* __restrict__ b2,
                                                     float* __restrict__ out) {
    __shared__ unsigned char As[2][4096];     // 4 m-frags, frag-major (1 KB/frag)

    const int t = threadIdx.x;
    const int bx = blockIdx.x;
    const int mt = (bx & 7) * 62 + (bx >> 3);    // XCD-chunked, bijective (496=8*62)
    const int m0A = mt << 7;                     // tile0 rows
    const int m0B = m0A + 64;                    // tile1 rows

    const int wave = t >> 6, lane = t & 63;      // wave = N group (128 cols)

    // ---- A-build mapping for both tiles: thread -> (pair row, 8-elem k-slice)
    const int arow = t >> 2;         // 0..63
    const int ks = t & 3;            // k-slice
    const unsigned short *uptrA, *vptrA, *uptrB, *vptrB;
    {
        int m = m0A + arow;
        int b = m / 992, p = m - b * 992;
        int i = p / 31, r = p - i * 31;
        int j = r + (r >= i ? 1 : 0);
        uptrA = UVb + (size_t)(b * 32 + i) * 1024 + ks * 8;
        vptrA = UVb + (size_t)(b * 32 + j) * 1024 + 512 + ks * 8;
        m = m0B + arow;
        b = m / 992; p = m - b * 992;
        i = p / 31; r = p - i * 31;
        j = r + (r >= i ? 1 : 0);
        uptrB = UVb + (size_t)(b * 32 + i) * 1024 + ks * 8;
        vptrB = UVb + (size_t)(b * 32 + j) * 1024 + 512 + ks * 8;
    }
    // frag-major write: frag = arow>>4, lane = ks*16 + (arow&15)
    const int awoff = (arow >> 4) * 1024 + (ks * 16 + (arow & 15)) * 16;

    // per-wave B source: frag (wave*8+n), lane slot
    const unsigned char* bsrc = (const unsigned char*)W2r +
                                (size_t)(wave * 8) * 1024 + lane * 16;

    const int cr = lane >> 4;
    const int cc = lane & 15;

    f32x4 acc[8][4] = {};            // 8 N-frags x 4 M-frags

    u32x4 Pub, Pvb;                  // UV ping (8 bf16 each)
    u32x4 Qub, Qvb;                  // UV pong
    bf16x8 Bp[8], Bq[8];             // B fragment double buffer (regs)

#define LOAD_B(S, DST)                                                         \
    {                                                                          \
        const unsigned char* gb = bsrc + (size_t)((S) & 15) * 32768;           \
        _Pragma("unroll")                                                      \
        for (int n = 0; n < 8; ++n)                                            \
            DST[n] = *(const bf16x8*)(gb + n * 1024);                          \
    }

#define LOAD_UV(S, Ub, Vb)                                                     \
    {                                                                          \
        const unsigned short* up = (((S) >= 16) ? uptrB : uptrA) + ((S) & 15) * 32; \
        const unsigned short* vp = (((S) >= 16) ? vptrB : vptrA) + ((S) & 15) * 32; \
        Ub = *(const u32x4*)up;                                                \
        Vb = *(const u32x4*)vp;                                                \
    }

// unpack bf16 pair, add, relu, repack
#define BUILD_A(DSTBUF, Ub, Vb)                                                \
    {                                                                          \
        u32x4 P;                                                               \
        _Pragma("unroll")                                                      \
        for (int q = 0; q < 4; ++q) {                                          \
            uint32_t uw = Ub[q], vw = Vb[q];                                   \
            uint32_t t0, t1;                                                   \
            float ul, uh, vl, vh;                                              \
            t0 = uw << 16; t1 = uw & 0xFFFF0000u;                              \
            __builtin_memcpy(&ul, &t0, 4); __builtin_memcpy(&uh, &t1, 4);      \
            t0 = vw << 16; t1 = vw & 0xFFFF0000u;                              \
            __builtin_memcpy(&vl, &t0, 4); __builtin_memcpy(&vh, &t1, 4);      \
            P[q] = cvt2_bf16(fmaxf(ul + vl, 0.0f), fmaxf(uh + vh, 0.0f));      \
        }                                                                      \
        *(u32x4*)(&As[DSTBUF][0] + awoff) = P;                                 \
    }

#define MFMA_STEP(BUF, BREG)                                                   \
    {                                                                          \
        const unsigned char* aB = &As[BUF][0];                                 \
        bf16x8 af[4];                                                          \
        _Pragma("unroll")                                                      \
        for (int m = 0; m < 4; ++m)                                            \
            af[m] = *(const bf16x8*)(aB + m * 1024 + lane * 16);               \
        __builtin_amdgcn_s_setprio(1);                                         \
        _Pragma("unroll")                                                      \
        for (int n = 0; n < 8; ++n)                                            \
            _Pragma("unroll")                                                  \
            for (int m = 0; m < 4; ++m)                                        \
                acc[n][m] = __builtin_amdgcn_mfma_f32_16x16x32_bf16(           \
                    af[m], BREG[n], acc[n][m], 0, 0, 0);                       \
        __builtin_amdgcn_s_setprio(0);                                         \
    }

#define EPILOGUE(M0, CLEAR)                                                    \
    {                                                                          \
        _Pragma("unroll")                                                      \
        for (int n = 0; n < 8; ++n) {                                          \
            int col = wave * 128 + n * 16 + cc;                                \
            float bias = b2[col];                                              \
            _Pragma("unroll")                                                  \
            for (int m = 0; m < 4; ++m) {                                      \
                int rowb = (M0) + m * 16 + cr * 4;                             \
                _Pragma("unroll")                                              \
                for (int r_ = 0; r_ < 4; ++r_) {                               \
                    out[(size_t)(rowb + r_) * 512 + col] = acc[n][m][r_] + bias;\
                    if (CLEAR) acc[n][m][r_] = 0.0f;                           \
                }                                                              \
            }                                                                  \
        }                                                                      \
    }

// lgkm-only barrier: A-tile ds ops synced; global prefetch loads ride through.
#define BARRIER() asm volatile("s_waitcnt lgkmcnt(0)\n\ts_barrier" ::: "memory")

    // ---- prologue: B(0)->Bp; UV(0)->P; UV(1)->Q; build A(0) from P.
    LOAD_B(0, Bp);
    LOAD_UV(0, Pub, Pvb);
    LOAD_UV(1, Qub, Qvb);
    BUILD_A(0, Pub, Pvb);

#pragma unroll 1
    for (int s2 = 0; s2 < 32; s2 += 2) {
        // ======== even step s = s2 (A buf 0, B in Bp) ========
        BARRIER();
        LOAD_B(s2 + 1, Bq);                              // s2+1 <= 31, valid
        if (s2 < 30) LOAD_UV(s2 + 2, Pub, Pvb);
        MFMA_STEP(0, Bp);
        BUILD_A(1, Qub, Qvb);                            // Q = UV(s2+1)

        // ======== odd step s = s2+1 (A buf 1, B in Bq) ========
        BARRIER();
        if (s2 < 30) LOAD_B(s2 + 2, Bp);
        if (s2 < 30) LOAD_UV(s2 + 3, Qub, Qvb);          // last-consumer guard
        MFMA_STEP(1, Bq);
        if (s2 < 30) BUILD_A(0, Pub, Pvb);               // P = UV(s2+2)

        // ---- tile-0 epilogue after step 15: stores drain under tile-1
        if (s2 == 14) EPILOGUE(m0A, 1);
    }
#undef LOAD_B
#undef LOAD_UV
#undef BUILD_A
#undef MFMA_STEP
#undef BARRIER

    // ---- tile-1 epilogue
    EPILOGUE(m0B, 0);
#undef EPILOGUE
}

// ---------------------------------------------------------------------------
extern "C" void kernel_launch(void* const* d_in, const int* in_sizes, int n_in,
                              void* d_out, int out_size, void* d_ws, size_t ws_size,
                              hipStream_t stream) {
    const float* pf = (const float*)d_in[0];   // (64, 32, 512)
    const float* W1 = (const float*)d_in[1];   // (512, 1024)
    const float* b1 = (const float*)d_in[2];   // (512,)
    const float* W2 = (const float*)d_in[3];   // (512, 512)
    const float* b2 = (const float*)d_in[4];   // (512,)
    float* out = (float*)d_out;                // (64, 992, 512)

    unsigned short* UVb = (unsigned short*)d_ws;                    // 4 MB (bf16)
    unsigned short* W2r = (unsigned short*)((char*)d_ws + (size_t)8 * 1024 * 1024); // 512 KB

    prep<<<dim3(640), dim3(256), 0, stream>>>(pf, W1, b1, W2, UVb, W2r);
    fused_gemm<<<dim3(496), dim3(256), 0, stream>>>(UVb, W2r, b2, out);
}

// Round 20
// 67.790 us; speedup vs baseline: 1.3371x; 1.3371x over previous
//
#include <hip/hip_runtime.h>
#include <hip/hip_bf16.h>
#include <stdint.h>

// Problem: B=64, N=32, D=512, P=992 pairs, M = B*P = 63488.
// out[m,d] = relu(U[i(m)] + V[j(m)])·W2[d,:] + b2[d]
// U = pf @ W1[:,:512]^T (+b1), V = pf @ W1[:,512:]^T   (only 2048 distinct rows)
//
// Config ledger:
//   R7:  BN<512 col-split -> L2 thrash. BN=512 mandatory.
//   R8:  2 independent blocks/CU give phase overlap; 1 barrier-locked block
//        serializes (R4-R6, re-confirmed R14).
//   R9:  ping-pong guards must cover the LAST consumer.
//   R11: __launch_bounds__ 2nd arg = waves per SIMD, NOT blocks/CU.
//   R13: B global->VGPR; lgkm-only barrier lets prefetch ride through.
//   R14: BM=128 -> 1 block/CU -> regressed. acc=128 + 2 blocks/CU is fixed.
//   R15: NT stores regressed. R16: setprio removal regressed (keep setprio).
//   R18: bf16 UV end-to-end: 73.4 -> 71.6 us (traffic model holds). BEST.
//   R19: mid-loop bulk epilogue REGRESSED (90.6): stores share the in-order
//        vmcnt queue with loads -> counted waits drain the store burst on
//        the critical path. No mid-loop bulk stores.
//   R20: 4-deep A buffer, barrier every 2 steps (halve barrier overhead).

typedef __attribute__((ext_vector_type(4))) float f32x4;
typedef __attribute__((ext_vector_type(8))) short bf16x8;
typedef __attribute__((ext_vector_type(4))) unsigned int u32x4;

__device__ __forceinline__ uint32_t cvt2_bf16(float a, float b) {
    __hip_bfloat162 h = __float22bfloat162_rn(make_float2(a, b));
    uint32_t u;
    __builtin_memcpy(&u, &h, 4);
    return u;
}

// ---------------------------------------------------------------------------
// Kernel 1 (merged): blocks 0..511 -> uv_gemm 32x128 tiles (2.5 blocks/CU);
// blocks 512..639 -> W2 rearrange into MFMA-fragment order (32768 16B slots):
//   slot s: l = s&63, fn = (s>>6)&31, kt = s>>11
//   col = fn*16 + (l&15), k = kt*32 + (l>>4)*8
// UV stored in BF16: UVb[row][0..511]=U row (b1 folded), [512..1023]=V.
// ---------------------------------------------------------------------------
__global__ __launch_bounds__(256) void prep(const float* __restrict__ pf,
                                            const float* __restrict__ W1,
                                            const float* __restrict__ b1,
                                            const float* __restrict__ W2,
                                            unsigned short* __restrict__ UVb,
                                            unsigned short* __restrict__ W2r) {
    __shared__ unsigned short As[32][64];
    __shared__ unsigned short Bs[128][64];

    const int t = threadIdx.x;
    const int bxg = blockIdx.x;

    if (bxg >= 512) {
        int s = (bxg - 512) * 256 + t;           // 0..32767
        int l = s & 63;
        int fn = (s >> 6) & 31;
        int kt = s >> 11;
        int col = fn * 16 + (l & 15);
        int k = kt * 32 + (l >> 4) * 8;
        const float* src = W2 + (size_t)col * 512 + k;
        f32x4 a = ((const f32x4*)src)[0];
        f32x4 b = ((const f32x4*)src)[1];
        u32x4 P;
        P[0] = cvt2_bf16(a[0], a[1]); P[1] = cvt2_bf16(a[2], a[3]);
        P[2] = cvt2_bf16(b[0], b[1]); P[3] = cvt2_bf16(b[2], b[3]);
        *(u32x4*)(W2r + (size_t)s * 8) = P;
        return;
    }

    // ---- uv_gemm: 32x128 tile, BK=64, 4 waves (2M x 2N), XOR-swizzled LDS
    const int m0 = (bxg >> 3) * 32;              // 64 m-tiles
    const int c0 = (bxg & 7) * 128;              // 8 col tiles

    const int row8 = t >> 3;                     // 0..31
    const int g = t & 7;                         // 16B granule (8 floats)

    const int wave = t >> 6, lane = t & 63;
    const int wr = wave >> 1, wc = wave & 1;
    const int lr = lane & 15, lkq = lane >> 4;
    const int s7 = lr & 7;

    f32x4 acc[4] = {};

    const float* a_src = pf + (size_t)(m0 + row8) * 512 + g * 8;
    const float* b_src[4];
    int wbB[4];
#pragma unroll
    for (int p = 0; p < 4; ++p) {
        int rb = p * 32 + row8;
        int c = c0 + rb;
        int d = c & 511;
        int koff = (c >> 9) * 512;
        b_src[p] = W1 + (size_t)d * 1024 + koff + g * 8;
        wbB[p] = rb * 128 + ((g ^ (rb & 7)) << 4);
    }
    const int wbA = row8 * 128 + ((g ^ (row8 & 7)) << 4);

    for (int kt = 0; kt < 512; kt += 64) {
        {
            const float* gp = a_src + kt;
            f32x4 x0 = ((const f32x4*)gp)[0];
            f32x4 x1 = ((const f32x4*)gp)[1];
            u32x4 P;
            P[0] = cvt2_bf16(x0[0], x0[1]); P[1] = cvt2_bf16(x0[2], x0[3]);
            P[2] = cvt2_bf16(x1[0], x1[1]); P[3] = cvt2_bf16(x1[2], x1[3]);
            *(u32x4*)((char*)&As[0][0] + wbA) = P;
        }
#pragma unroll
        for (int p = 0; p < 4; ++p) {
            const float* gp = b_src[p] + kt;
            f32x4 x0 = ((const f32x4*)gp)[0];
            f32x4 x1 = ((const f32x4*)gp)[1];
            u32x4 P;
            P[0] = cvt2_bf16(x0[0], x0[1]); P[1] = cvt2_bf16(x0[2], x0[3]);
            P[2] = cvt2_bf16(x1[0], x1[1]); P[3] = cvt2_bf16(x1[2], x1[3]);
            *(u32x4*)((char*)&Bs[0][0] + wbB[p]) = P;
        }
        __syncthreads();
#pragma unroll
        for (int kk = 0; kk < 2; ++kk) {
            const int co = (((kk << 2) + lkq) ^ s7) << 3;    // ushort offset
            bf16x8 af = *(const bf16x8*)(&As[0][0] + (wr * 16 + lr) * 64 + co);
#pragma unroll
            for (int n = 0; n < 4; ++n) {
                bf16x8 bfr = *(const bf16x8*)(&Bs[0][0] + (wc * 64 + n * 16 + lr) * 64 + co);
                acc[n] = __builtin_amdgcn_mfma_f32_16x16x32_bf16(af, bfr, acc[n], 0, 0, 0);
            }
        }
        __syncthreads();
    }

    const int cr = lane >> 4;
    const int cc = lane & 15;
#pragma unroll
    for (int n = 0; n < 4; ++n) {
        int c = c0 + wc * 64 + n * 16 + cc;
        float bias = (c < 512) ? b1[c] : 0.0f;
        int rowb = m0 + wr * 16 + cr * 4;
#pragma unroll
        for (int r_ = 0; r_ < 4; ++r_)
            UVb[(size_t)(rowb + r_) * 1024 + c] =
                (unsigned short)(cvt2_bf16(acc[n][r_] + bias, 0.0f) & 0xFFFFu);
    }
}

// ---------------------------------------------------------------------------
// Kernel 2: out = relu(U[i]+V[j]) @ W2^T + b2.  (R18 structure + R20: 4-deep
// A buffer, ONE barrier per 2 steps.)
// BM=64, BN=512, BK=32, 16 steps. 256 thr = 4 waves, wave tile 64x128.
// B: global->VGPR dbuf, reloaded right after last use. UV: bf16 ping-pong.
// A: 16 KB frag-major 4-buf LDS; barrier = lgkmcnt(0)+s_barrier only.
// Hazards: buf (s+2)&3 rewritten at epoch s, last read epoch s-2 -> one
// barrier between (WAR ok); reads cross exactly one barrier (RAW ok).
// 2 blocks/CU. Grid 992 = 8 XCD x 124 m-tiles.
// ---------------------------------------------------------------------------
__global__ __launch_bounds__(256, 2) void fused_gemm(const unsigned short* __restrict__ UVb,
                                                     const unsigned short* __restrict__ W2r,
                                                     const float* __restrict__ b2,
                                                     float* __restrict__ out) {
    __shared__ unsigned char As[4][4096];     // 4 m-frags/buf, frag-major

    const int t = threadIdx.x;
    const int bx = blockIdx.x;
    const int mt = (bx & 7) * 124 + (bx >> 3);   // XCD-chunked, bijective (992=8*124)
    const int m0 = mt << 6;

    const int wave = t >> 6, lane = t & 63;      // wave = N group (128 cols)

    // ---- A-build mapping: thread -> (pair row, 8-elem k-slice), bf16 UV
    const int arow = t >> 2;         // 0..63
    const int ks = t & 3;            // k-slice
    const unsigned short* uptr;
    const unsigned short* vptr;
    {
        int m = m0 + arow;
        int b = m / 992, p = m - b * 992;
        int i = p / 31, r = p - i * 31;
        int j = r + (r >= i ? 1 : 0);
        uptr = UVb + (size_t)(b * 32 + i) * 1024 + ks * 8;
        vptr = UVb + (size_t)(b * 32 + j) * 1024 + 512 + ks * 8;
    }
    // frag-major write: frag = arow>>4, lane = ks*16 + (arow&15)
    const int awoff = (arow >> 4) * 1024 + (ks * 16 + (arow & 15)) * 16;

    // per-wave B source: frag (wave*8+n), lane slot
    const unsigned char* bsrc = (const unsigned char*)W2r +
                                (size_t)(wave * 8) * 1024 + lane * 16;

    const int cr = lane >> 4;
    const int cc = lane & 15;

    f32x4 acc[8][4] = {};            // 8 N-frags x 4 M-frags

    u32x4 Pub, Pvb;                  // UV ping (8 bf16 each)
    u32x4 Qub, Qvb;                  // UV pong
    bf16x8 Bp[8], Bq[8];             // B fragment double buffer (regs)

#define LOAD_B(S, DST)                                                         \
    {                                                                          \
        const unsigned char* gb = bsrc + (size_t)(S) * 32768;                  \
        _Pragma("unroll")                                                      \
        for (int n = 0; n < 8; ++n)                                            \
            DST[n] = *(const bf16x8*)(gb + n * 1024);                          \
    }

#define LOAD_UV(S, Ub, Vb)                                                     \
    {                                                                          \
        Ub = *(const u32x4*)(uptr + (S) * 32);                                 \
        Vb = *(const u32x4*)(vptr + (S) * 32);                                 \
    }

// unpack bf16 pair, add, relu, repack
#define BUILD_A(DSTBUF, Ub, Vb)                                                \
    {                                                                          \
        u32x4 P;                                                               \
        _Pragma("unroll")                                                      \
        for (int q = 0; q < 4; ++q) {                                          \
            uint32_t uw = Ub[q], vw = Vb[q];                                   \
            uint32_t t0, t1;                                                   \
            float ul, uh, vl, vh;                                              \
            t0 = uw << 16; t1 = uw & 0xFFFF0000u;                              \
            __builtin_memcpy(&ul, &t0, 4); __builtin_memcpy(&uh, &t1, 4);      \
            t0 = vw << 16; t1 = vw & 0xFFFF0000u;                              \
            __builtin_memcpy(&vl, &t0, 4); __builtin_memcpy(&vh, &t1, 4);      \
            P[q] = cvt2_bf16(fmaxf(ul + vl, 0.0f), fmaxf(uh + vh, 0.0f));      \
        }                                                                      \
        *(u32x4*)(&As[DSTBUF][0] + awoff) = P;                                 \
    }

#define MFMA_STEP(BUF, BREG)                                                   \
    {                                                                          \
        const unsigned char* aB = &As[BUF][0];                                 \
        bf16x8 af[4];                                                          \
        _Pragma("unroll")                                                      \
        for (int m = 0; m < 4; ++m)                                            \
            af[m] = *(const bf16x8*)(aB + m * 1024 + lane * 16);               \
        __builtin_amdgcn_s_setprio(1);                                         \
        _Pragma("unroll")                                                      \
        for (int n = 0; n < 8; ++n)                                            \
            _Pragma("unroll")                                                  \
            for (int m = 0; m < 4; ++m)                                        \
                acc[n][m] = __builtin_amdgcn_mfma_f32_16x16x32_bf16(           \
                    af[m], BREG[n], acc[n][m], 0, 0, 0);                       \
        __builtin_amdgcn_s_setprio(0);                                         \
    }

// lgkm-only barrier: A-tile ds ops synced; global prefetch loads ride through.
#define BARRIER() asm volatile("s_waitcnt lgkmcnt(0)\n\ts_barrier" ::: "memory")

    // ---- prologue: B(0)->Bp, B(1)->Bq; UV(0)->P, UV(1)->Q; build A0, A1.
    LOAD_B(0, Bp);
    LOAD_B(1, Bq);
    LOAD_UV(0, Pub, Pvb);
    LOAD_UV(1, Qub, Qvb);
    BUILD_A(0, Pub, Pvb);
    BUILD_A(1, Qub, Qvb);

#pragma unroll 1
    for (int s2 = 0; s2 < 16; s2 += 2) {
        // ---- epoch = steps s2, s2+1; ONE barrier.
        // At barrier: A[s2&3], A[(s2+1)&3] built; B(s2) in Bp, B(s2+1) in Bq.
        BARRIER();
        if (s2 < 14) {
            LOAD_UV(s2 + 2, Pub, Pvb);
            LOAD_UV(s2 + 3, Qub, Qvb);
        }
        MFMA_STEP(s2 & 3, Bp);
        if (s2 < 14) LOAD_B(s2 + 2, Bp);                 // reload after last use
        MFMA_STEP((s2 + 1) & 3, Bq);
        if (s2 < 14) {
            LOAD_B(s2 + 3, Bq);
            BUILD_A((s2 + 2) & 3, Pub, Pvb);
            BUILD_A((s2 + 3) & 3, Qub, Qvb);
        }
    }
#undef LOAD_B
#undef LOAD_UV
#undef BUILD_A
#undef MFMA_STEP
#undef BARRIER

    // ---- epilogue: C/D layout col=lane&15, row=(lane>>4)*4+reg
#pragma unroll
    for (int n = 0; n < 8; ++n) {
        int col = wave * 128 + n * 16 + cc;
        float bias = b2[col];
#pragma unroll
        for (int m = 0; m < 4; ++m) {
            int rowb = m0 + m * 16 + cr * 4;
#pragma unroll
            for (int r_ = 0; r_ < 4; ++r_)
                out[(size_t)(rowb + r_) * 512 + col] = acc[n][m][r_] + bias;
        }
    }
}

// ---------------------------------------------------------------------------
extern "C" void kernel_launch(void* const* d_in, const int* in_sizes, int n_in,
                              void* d_out, int out_size, void* d_ws, size_t ws_size,
                              hipStream_t stream) {
    const float* pf = (const float*)d_in[0];   // (64, 32, 512)
    const float* W1 = (const float*)d_in[1];   // (512, 1024)
    const float* b1 = (const float*)d_in[2];   // (512,)
    const float* W2 = (const float*)d_in[3];   // (512, 512)
    const float* b2 = (const float*)d_in[4];   // (512,)
    float* out = (float*)d_out;                // (64, 992, 512)

    unsigned short* UVb = (unsigned short*)d_ws;                    // 4 MB (bf16)
    unsigned short* W2r = (unsigned short*)((char*)d_ws + (size_t)8 * 1024 * 1024); // 512 KB

    prep<<<dim3(640), dim3(256), 0, stream>>>(pf, W1, b1, W2, UVb, W2r);
    fused_gemm<<<dim3(992), dim3(256), 0, stream>>>(UVb, W2r, b2, out);
}